// Round 10
// baseline (404.446 us; speedup 1.0000x reference)
//
#include <hip/hip_runtime.h>

#define ALIGNUP(x) (((x) + 255) & ~(size_t)255)
#define ABLK 256          // blocks for hist/scatter passes
#define BSHIFT 9          // 512 dst nodes per bucket; requires N <= 131072

typedef _Float16 f16x8 __attribute__((ext_vector_type(8)));
typedef float f32x4 __attribute__((ext_vector_type(4)));

// ---------------- CSR build: two-level counting sort, LDS atomics only ----------------

__global__ void bucket_hist_kernel(const int* __restrict__ col, unsigned* __restrict__ gHist,
                                   int nE, int chunk) {
    __shared__ unsigned hist[256];
    const int tid = threadIdx.x, blk = blockIdx.x;
    hist[tid] = 0;
    __syncthreads();
    const int e0 = blk * chunk, e1 = min(nE, e0 + chunk);
    for (int e = e0 + tid; e < e1; e += 256)
        atomicAdd(&hist[((unsigned)col[e]) >> BSHIFT], 1u);
    __syncthreads();
    gHist[tid * ABLK + blk] = hist[tid];   // bucket-major
}

__global__ void bucket_scan_kernel(unsigned* __restrict__ g) {
    __shared__ unsigned ps[1024];
    const int tid = threadIdx.x;
    const int base = tid * 64;
    unsigned sum = 0;
    for (int k = 0; k < 64; ++k) sum += g[base + k];
    ps[tid] = sum;
    __syncthreads();
    for (int o = 1; o < 1024; o <<= 1) {
        unsigned t = tid >= o ? ps[tid - o] : 0u;
        __syncthreads();
        ps[tid] += t;
        __syncthreads();
    }
    unsigned run = ps[tid] - sum;
    for (int k = 0; k < 64; ++k) {
        unsigned v = g[base + k];
        g[base + k] = run;
        run += v;
    }
}

__global__ void bucket_scatter_kernel(const int* __restrict__ row, const int* __restrict__ col,
                                      const unsigned* __restrict__ gScan,
                                      unsigned* __restrict__ pairs, int nE, int chunk) {
    __shared__ unsigned basec[256];
    const int tid = threadIdx.x, blk = blockIdx.x;
    basec[tid] = gScan[tid * ABLK + blk];
    __syncthreads();
    const int e0 = blk * chunk, e1 = min(nE, e0 + chunk);
    for (int e = e0 + tid; e < e1; e += 256) {
        unsigned d = (unsigned)col[e];
        unsigned pos = atomicAdd(&basec[d >> BSHIFT], 1u);
        pairs[pos] = (((unsigned)row[e]) << BSHIFT) | (d & 511u);  // src(17b) | dstLow(9b)
    }
}

__global__ void bucket_sort_kernel(const unsigned* __restrict__ pairs,
                                   const unsigned* __restrict__ gScan,
                                   int* __restrict__ srcs, int* __restrict__ off,
                                   float* __restrict__ dinv, int nN, int nE) {
    __shared__ unsigned cnt[512], sc[512];
    const int tid = threadIdx.x, b = blockIdx.x;
    const unsigned s = gScan[b * ABLK];
    const unsigned t = (b + 1 < 256) ? gScan[(b + 1) * ABLK] : (unsigned)nE;
    cnt[tid] = 0;
    __syncthreads();
    for (unsigned i = s + tid; i < t; i += 512)
        atomicAdd(&cnt[pairs[i] & 511u], 1u);
    __syncthreads();
    const unsigned v = cnt[tid];
    sc[tid] = v;
    __syncthreads();
    for (int o = 1; o < 512; o <<= 1) {
        unsigned q = tid >= o ? sc[tid - o] : 0u;
        __syncthreads();
        sc[tid] += q;
        __syncthreads();
    }
    const unsigned excl = sc[tid] - v;
    const int node = b * 512 + tid;
    if (node < nN) {
        dinv[node] = v > 0 ? rsqrtf((float)v) : 0.f;
        off[node] = (int)(s + excl);
    }
    if (b == 0 && tid == 0) off[nN] = nE;
    sc[tid] = excl;          // reuse as cursor
    __syncthreads();
    for (unsigned i = s + tid; i < t; i += 512) {
        unsigned p = pairs[i];
        unsigned pos = s + atomicAdd(&sc[p & 511u], 1u);
        srcs[pos] = (int)(p >> BSHIFT);
    }
}

// -------- W -> fragment-order f16 in GLOBAL memory (once per layer, tiny) --------

template <int DOUT>
__global__ void wf_prep_kernel(const float* __restrict__ W, f16x8* __restrict__ Wf) {
    const int c = blockIdx.x * blockDim.x + threadIdx.x;
    if (c >= DOUT * 16) return;
    const int l = c & 63;
    const int fk = (c >> 6) & 3;
    const int j = c >> 8;
    const int n = j * 16 + (l & 15);
    const int kbase = fk * 32 + ((l >> 4) * 8);
    f16x8 v;
#pragma unroll
    for (int e = 0; e < 8; ++e)
        v[e] = (_Float16)W[(size_t)(kbase + e) * DOUT + n];
    Wf[c] = v;
}

// -------- MFMA GEMM, LDS-free, PLANE-MAJOR output --------
// Yp[j] is a [nrows][16] f16 plane (3.2MB): plane j holds features j*16..j*16+15.
// b-fragments from global Wf (L2-resident, coalesced). A row = lane&15, k-chunks by
// lane>>4. C/D: col=lane&15, row=(lane>>4)*4+reg.

template <int DOUT, bool AF32>
__launch_bounds__(256)
__global__ void gemm_mfma(const void* __restrict__ Xv, const f16x8* __restrict__ Wf,
                          const float* __restrict__ dinv, _Float16* __restrict__ Y, int nrows) {
    constexpr int NTILE = DOUT / 16;
    const int lane = threadIdx.x & 63;
    const int wvid = threadIdx.x >> 6;
    const int m = lane & 15;
    const int kb = lane >> 4;
    const int r0 = blockIdx.x * 64 + wvid * 16;
    if (r0 >= nrows) return;
    const int arow = min(r0 + m, nrows - 1);
    const size_t PS = (size_t)nrows * 16;   // plane stride (elements)

    f16x8 a[4];
    if constexpr (AF32) {
        const float* Xp = (const float*)Xv + (size_t)arow * 128 + kb * 8;
#pragma unroll
        for (int k = 0; k < 4; ++k) {
            const float4 x0 = *(const float4*)(Xp + k * 32);
            const float4 x1 = *(const float4*)(Xp + k * 32 + 4);
            f16x8 t;
            t[0] = (_Float16)x0.x; t[1] = (_Float16)x0.y;
            t[2] = (_Float16)x0.z; t[3] = (_Float16)x0.w;
            t[4] = (_Float16)x1.x; t[5] = (_Float16)x1.y;
            t[6] = (_Float16)x1.z; t[7] = (_Float16)x1.w;
            a[k] = t;
        }
    } else {
        const _Float16* Xp = (const _Float16*)Xv + (size_t)arow * 128 + kb * 8;
#pragma unroll
        for (int k = 0; k < 4; ++k) a[k] = *(const f16x8*)(Xp + k * 32);
    }

    f32x4 acc[NTILE];
#pragma unroll
    for (int j = 0; j < NTILE; ++j) acc[j] = (f32x4){0.f, 0.f, 0.f, 0.f};
#pragma unroll
    for (int k = 0; k < 4; ++k)
#pragma unroll
        for (int j = 0; j < NTILE; ++j)
            acc[j] = __builtin_amdgcn_mfma_f32_16x16x32_f16(
                         a[k], Wf[(j * 4 + k) * 64 + lane], acc[j], 0, 0, 0);

#pragma unroll
    for (int i = 0; i < 4; ++i) {
        const int r = r0 + kb * 4 + i;
        if (r < nrows) {
            const float dv = dinv[r];
#pragma unroll
            for (int j = 0; j < NTILE; ++j)
                Y[(size_t)j * PS + (size_t)r * 16 + m] = (_Float16)(acc[j][i] * dv);
        }
    }
}

// -------- XCD-sliced CSR gather --------
// XWp is plane-major: NSLICE planes of [nN][16] f16 (3.2MB each). slice = bid & (NSLICE-1)
// -> with round-robin block->XCD dispatch, all blocks reading plane s run on XCD s, whose
// 4MB L2 then holds the whole plane: random src-row reads become L2 hits after first touch.
// 2-lane groups per dst node: lane pl owns 8 feats (16B); src indices shfl-broadcast.
// Output written NODE-major (feeds next gemm / d_out).

template <int NSLICE, typename OT>
__launch_bounds__(256)
__global__ void gather_xcd(const _Float16* __restrict__ XWp, const int* __restrict__ off,
                           const int* __restrict__ srcs, const float* __restrict__ dinv,
                           const float* __restrict__ bias, OT* __restrict__ out, int nN) {
    const int bid = blockIdx.x;
    const int s = bid & (NSLICE - 1);
    const int chunk = bid / NSLICE;
    const int tid = threadIdx.x;
    const int lane = tid & 63;
    const int pl = lane & 1;                  // 16B half within the 32B slice
    const int v = chunk * 128 + (tid >> 1);   // 128 groups of 2 lanes per block
    const bool act = v < nN;

    const _Float16* plane = XWp + (size_t)s * nN * 16;
    const int s0 = act ? off[v] : 0;
    const int s1 = act ? off[v + 1] : 0;

    float acc[8];
#pragma unroll
    for (int k = 0; k < 8; ++k) acc[k] = 0.f;

    int base = s0;
    while (base + 2 <= s1) {                  // pair-uniform condition
        const int myidx = srcs[base + pl];
#pragma unroll
        for (int j = 0; j < 2; ++j) {
            const int src = __shfl(myidx, (lane & 62) | j);
            union { uint4 u; _Float16 h[8]; } cv;
            cv.u = *(const uint4*)(plane + (size_t)src * 16 + pl * 8);
#pragma unroll
            for (int k = 0; k < 8; ++k) acc[k] += (float)cv.h[k];
        }
        base += 2;
    }
    if (base < s1) {                          // odd tail: both lanes load same addr
        const int src = srcs[base];
        union { uint4 u; _Float16 h[8]; } cv;
        cv.u = *(const uint4*)(plane + (size_t)src * 16 + pl * 8);
#pragma unroll
        for (int k = 0; k < 8; ++k) acc[k] += (float)cv.h[k];
    }

    if (act) {
        const float dv = dinv[v];
        const float4 b0 = ((const float4*)bias)[s * 4 + pl * 2];
        const float4 b1 = ((const float4*)bias)[s * 4 + pl * 2 + 1];
        float o[8];
        o[0] = fmaxf(dv * acc[0] + b0.x, 0.f);
        o[1] = fmaxf(dv * acc[1] + b0.y, 0.f);
        o[2] = fmaxf(dv * acc[2] + b0.z, 0.f);
        o[3] = fmaxf(dv * acc[3] + b0.w, 0.f);
        o[4] = fmaxf(dv * acc[4] + b1.x, 0.f);
        o[5] = fmaxf(dv * acc[5] + b1.y, 0.f);
        o[6] = fmaxf(dv * acc[6] + b1.z, 0.f);
        o[7] = fmaxf(dv * acc[7] + b1.w, 0.f);
        if constexpr (sizeof(OT) == 2) {
            union { uint4 u; _Float16 h[8]; } ov;
#pragma unroll
            for (int k = 0; k < 8; ++k) ov.h[k] = (_Float16)o[k];
            *(uint4*)((_Float16*)out + (size_t)v * (NSLICE * 16) + s * 16 + pl * 8) = ov.u;
        } else {
            float* op = (float*)out + (size_t)v * (NSLICE * 16) + s * 16 + pl * 8;
            *(float4*)op       = make_float4(o[0], o[1], o[2], o[3]);
            *(float4*)(op + 4) = make_float4(o[4], o[5], o[6], o[7]);
        }
    }
}

extern "C" void kernel_launch(void* const* d_in, const int* in_sizes, int n_in,
                              void* d_out, int out_size, void* d_ws, size_t ws_size,
                              hipStream_t stream) {
    const float* feats = (const float*)d_in[0];
    const int*   ei    = (const int*)d_in[1];
    const float* W1    = (const float*)d_in[2];
    const float* b1    = (const float*)d_in[3];
    const float* W2    = (const float*)d_in[4];
    const float* b2    = (const float*)d_in[5];
    const float* W3    = (const float*)d_in[6];
    const float* b3    = (const float*)d_in[7];

    const int N = in_sizes[0] / 128;
    const int E = in_sizes[1] / 2;
    const int* row = ei;       // source
    const int* col = ei + E;   // destination

    // workspace layout
    char* p = (char*)d_ws;
    unsigned* gHist = (unsigned*)p; p += ALIGNUP((size_t)256 * ABLK * 4);
    float*     dinv = (float*)p;    p += ALIGNUP((size_t)N * 4);
    int*       off  = (int*)p;      p += ALIGNUP((size_t)(N + 1) * 4);
    int*       srcs = (int*)p;      p += ALIGNUP((size_t)E * 4);
    f16x8*     wf1  = (f16x8*)p;    p += ALIGNUP((size_t)128 * 16 * 16);
    f16x8*     wf2  = (f16x8*)p;    p += ALIGNUP((size_t)128 * 16 * 16);
    f16x8*     wf3  = (f16x8*)p;    p += ALIGNUP((size_t)64 * 16 * 16);
    _Float16*  bufW = (_Float16*)p; p += ALIGNUP((size_t)N * 128 * 2);   // XW planes
    _Float16*  bufX = (_Float16*)p;                                       // h (node-major)
    unsigned* pairs = (unsigned*)bufX;  // alias: pairs consumed before gather1 writes bufX

    // ---- W fragment prep ----
    wf_prep_kernel<128><<<8, 256, 0, stream>>>(W1, wf1);
    wf_prep_kernel<128><<<8, 256, 0, stream>>>(W2, wf2);
    wf_prep_kernel<64><<<4, 256, 0, stream>>>(W3, wf3);

    // ---- CSR build (no global atomics) ----
    const int chunk = (E + ABLK - 1) / ABLK;
    const int NB    = (N + 511) >> BSHIFT;
    bucket_hist_kernel<<<ABLK, 256, 0, stream>>>(col, gHist, E, chunk);
    bucket_scan_kernel<<<1, 1024, 0, stream>>>(gHist);
    bucket_scatter_kernel<<<ABLK, 256, 0, stream>>>(row, col, gHist, pairs, E, chunk);
    bucket_sort_kernel<<<NB, 512, 0, stream>>>(pairs, gHist, srcs, off, dinv, N, E);

    const int NCH  = (N + 63) / 64;         // gemm: 64-row chunks, one block each
    const int NCG  = (N + 127) / 128;       // gather node chunks (128 nodes/block)

    // ---- layer 1 ----
    gemm_mfma<128, true><<<NCH, 256, 0, stream>>>(feats, wf1, dinv, bufW, N);
    gather_xcd<8, _Float16><<<NCG * 8, 256, 0, stream>>>(bufW, off, srcs, dinv, b1, bufX, N);
    // ---- layer 2 ----
    gemm_mfma<128, false><<<NCH, 256, 0, stream>>>(bufX, wf2, dinv, bufW, N);
    gather_xcd<8, _Float16><<<NCG * 8, 256, 0, stream>>>(bufW, off, srcs, dinv, b2, bufX, N);
    // ---- layer 3: DOUT=64 (4 planes); agg -> d_out (f32 node-major) ----
    gemm_mfma<64, false><<<NCH, 256, 0, stream>>>(bufX, wf3, dinv, bufW, N);
    gather_xcd<4, float><<<NCG * 4, 256, 0, stream>>>(bufW, off, srcs, dinv, b3,
                                                      (float*)d_out, N);
}

// Round 11
// 292.936 us; speedup vs baseline: 1.3807x; 1.3807x over previous
//
#include <hip/hip_runtime.h>

#define ALIGNUP(x) (((x) + 255) & ~(size_t)255)
#define ABLK 256          // blocks for hist/scatter passes
#define BSHIFT 9          // 512 dst nodes per bucket; requires N <= 131072

typedef _Float16 f16x8 __attribute__((ext_vector_type(8)));
typedef float f32x4 __attribute__((ext_vector_type(4)));

// ---------------- CSR build: two-level counting sort, LDS atomics only ----------------

__global__ void bucket_hist_kernel(const int* __restrict__ col, unsigned* __restrict__ gHist,
                                   int nE, int chunk) {
    __shared__ unsigned hist[256];
    const int tid = threadIdx.x, blk = blockIdx.x;
    hist[tid] = 0;
    __syncthreads();
    const int e0 = blk * chunk, e1 = min(nE, e0 + chunk);
    for (int e = e0 + tid; e < e1; e += 256)
        atomicAdd(&hist[((unsigned)col[e]) >> BSHIFT], 1u);
    __syncthreads();
    gHist[tid * ABLK + blk] = hist[tid];   // bucket-major
}

__global__ void bucket_scan_kernel(unsigned* __restrict__ g) {
    __shared__ unsigned ps[1024];
    const int tid = threadIdx.x;
    const int base = tid * 64;
    unsigned sum = 0;
    for (int k = 0; k < 64; ++k) sum += g[base + k];
    ps[tid] = sum;
    __syncthreads();
    for (int o = 1; o < 1024; o <<= 1) {
        unsigned t = tid >= o ? ps[tid - o] : 0u;
        __syncthreads();
        ps[tid] += t;
        __syncthreads();
    }
    unsigned run = ps[tid] - sum;
    for (int k = 0; k < 64; ++k) {
        unsigned v = g[base + k];
        g[base + k] = run;
        run += v;
    }
}

__global__ void bucket_scatter_kernel(const int* __restrict__ row, const int* __restrict__ col,
                                      const unsigned* __restrict__ gScan,
                                      unsigned* __restrict__ pairs, int nE, int chunk) {
    __shared__ unsigned basec[256];
    const int tid = threadIdx.x, blk = blockIdx.x;
    basec[tid] = gScan[tid * ABLK + blk];
    __syncthreads();
    const int e0 = blk * chunk, e1 = min(nE, e0 + chunk);
    for (int e = e0 + tid; e < e1; e += 256) {
        unsigned d = (unsigned)col[e];
        unsigned pos = atomicAdd(&basec[d >> BSHIFT], 1u);
        pairs[pos] = (((unsigned)row[e]) << BSHIFT) | (d & 511u);  // src(17b) | dstLow(9b)
    }
}

__global__ void bucket_sort_kernel(const unsigned* __restrict__ pairs,
                                   const unsigned* __restrict__ gScan,
                                   int* __restrict__ srcs, int* __restrict__ off,
                                   float* __restrict__ dinv, int nN, int nE) {
    __shared__ unsigned cnt[512], sc[512];
    const int tid = threadIdx.x, b = blockIdx.x;
    const unsigned s = gScan[b * ABLK];
    const unsigned t = (b + 1 < 256) ? gScan[(b + 1) * ABLK] : (unsigned)nE;
    cnt[tid] = 0;
    __syncthreads();
    for (unsigned i = s + tid; i < t; i += 512)
        atomicAdd(&cnt[pairs[i] & 511u], 1u);
    __syncthreads();
    const unsigned v = cnt[tid];
    sc[tid] = v;
    __syncthreads();
    for (int o = 1; o < 512; o <<= 1) {
        unsigned q = tid >= o ? sc[tid - o] : 0u;
        __syncthreads();
        sc[tid] += q;
        __syncthreads();
    }
    const unsigned excl = sc[tid] - v;
    const int node = b * 512 + tid;
    if (node < nN) {
        dinv[node] = v > 0 ? rsqrtf((float)v) : 0.f;
        off[node] = (int)(s + excl);
    }
    if (b == 0 && tid == 0) off[nN] = nE;
    sc[tid] = excl;          // reuse as cursor
    __syncthreads();
    for (unsigned i = s + tid; i < t; i += 512) {
        unsigned p = pairs[i];
        unsigned pos = s + atomicAdd(&sc[p & 511u], 1u);
        srcs[pos] = (int)(p >> BSHIFT);
    }
}

// -------- W -> fragment-order f16 in GLOBAL memory (all 3 layers, one launch) --------
// Chunk cc = (j*4+k)*64 + lane holds the 16B b-fragment for n-tile j, k-step k, lane l:
// elements W[k*32 + (l>>4)*8 + e][j*16 + (l&15)], e=0..7.

__global__ void wf_prep_all(const float* __restrict__ W1, const float* __restrict__ W2,
                            const float* __restrict__ W3, f16x8* __restrict__ wf1,
                            f16x8* __restrict__ wf2, f16x8* __restrict__ wf3) {
    const int c = blockIdx.x * blockDim.x + threadIdx.x;
    const float* W; f16x8* Wf; int DOUT, cc;
    if (c < 2048)      { W = W1; Wf = wf1; DOUT = 128; cc = c; }
    else if (c < 4096) { W = W2; Wf = wf2; DOUT = 128; cc = c - 2048; }
    else if (c < 5120) { W = W3; Wf = wf3; DOUT = 64;  cc = c - 4096; }
    else return;
    const int l = cc & 63;
    const int fk = (cc >> 6) & 3;
    const int j = cc >> 8;
    const int n = j * 16 + (l & 15);
    const int kbase = fk * 32 + ((l >> 4) * 8);
    f16x8 v;
#pragma unroll
    for (int e = 0; e < 8; ++e)
        v[e] = (_Float16)W[(size_t)(kbase + e) * DOUT + n];
    Wf[cc] = v;
}

// -------- MFMA GEMM, LDS-free: Yh[r] = f16(dinv[r] * (X[r,128] @ W[128,DOUT])) --------
// b-fragments read directly from global Wf: lane-consecutive 16B = coalesced 1KB reads,
// L2-resident (32KB total). No staging, no barriers, one 64-row chunk per block.

template <int DOUT, bool AF32>
__launch_bounds__(256)
__global__ void gemm_mfma(const void* __restrict__ Xv, const f16x8* __restrict__ Wf,
                          const float* __restrict__ dinv, _Float16* __restrict__ Y, int nrows) {
    constexpr int NTILE = DOUT / 16;
    const int lane = threadIdx.x & 63;
    const int wvid = threadIdx.x >> 6;
    const int m = lane & 15;
    const int kb = lane >> 4;
    const int r0 = blockIdx.x * 64 + wvid * 16;
    if (r0 >= nrows) return;
    const int arow = min(r0 + m, nrows - 1);

    f16x8 a[4];
    if constexpr (AF32) {
        const float* Xp = (const float*)Xv + (size_t)arow * 128 + kb * 8;
#pragma unroll
        for (int k = 0; k < 4; ++k) {
            const float4 x0 = *(const float4*)(Xp + k * 32);
            const float4 x1 = *(const float4*)(Xp + k * 32 + 4);
            f16x8 t;
            t[0] = (_Float16)x0.x; t[1] = (_Float16)x0.y;
            t[2] = (_Float16)x0.z; t[3] = (_Float16)x0.w;
            t[4] = (_Float16)x1.x; t[5] = (_Float16)x1.y;
            t[6] = (_Float16)x1.z; t[7] = (_Float16)x1.w;
            a[k] = t;
        }
    } else {
        const _Float16* Xp = (const _Float16*)Xv + (size_t)arow * 128 + kb * 8;
#pragma unroll
        for (int k = 0; k < 4; ++k) a[k] = *(const f16x8*)(Xp + k * 32);
    }

    f32x4 acc[NTILE];
#pragma unroll
    for (int j = 0; j < NTILE; ++j) acc[j] = (f32x4){0.f, 0.f, 0.f, 0.f};
#pragma unroll
    for (int k = 0; k < 4; ++k)
#pragma unroll
        for (int j = 0; j < NTILE; ++j)
            acc[j] = __builtin_amdgcn_mfma_f32_16x16x32_f16(
                         a[k], Wf[(j * 4 + k) * 64 + lane], acc[j], 0, 0, 0);

#pragma unroll
    for (int i = 0; i < 4; ++i) {
        const int r = r0 + kb * 4 + i;
        if (r < nrows) {
            const float dv = dinv[r];
#pragma unroll
            for (int j = 0; j < NTILE; ++j)
                Y[(size_t)r * DOUT + j * 16 + m] = (_Float16)(acc[j][i] * dv);
        }
    }
}

// -------- grouped CSR gather, 16-deep MLP --------
// 64-wide slice per pass; blockIdx.y selects the feature half. 8 lanes own one dst node;
// src indices shfl-broadcast. Two 8-edge batches' loads (16 uint4) issue before any
// accumulate -> 16 outstanding misses/wave to hide L3 latency.

template <int LD, typename OT>
__launch_bounds__(256)
__global__ void gather_grp(const _Float16* __restrict__ XW, const int* __restrict__ off,
                           const int* __restrict__ srcs, const float* __restrict__ dinv,
                           const float* __restrict__ bias, OT* __restrict__ out, int nN) {
    constexpr int G = 8, GPW = 8;
    const int half = blockIdx.y;
    XW   += half * 64;
    bias += half * 64;
    out  += half * 64;
    const int lane = threadIdx.x & 63;
    const int gl   = lane % G;     // 16B chunk within the 64-wide slice
    const int grp  = lane / G;
    const int wid  = (blockIdx.x * blockDim.x + threadIdx.x) >> 6;
    const int nw   = (gridDim.x * blockDim.x) >> 6;

    for (int v0 = wid * GPW; v0 < nN; v0 += nw * GPW) {
        const int v   = v0 + grp;
        const bool act = v < nN;
        const int s0 = act ? off[v] : 0;
        const int s1 = act ? off[v + 1] : 0;
        float acc[8];
#pragma unroll
        for (int k = 0; k < 8; ++k) acc[k] = 0.f;

        int base = s0;
        while (base + 16 <= s1) {              // 16-deep: all loads before any accumulate
            const int ia = srcs[base + gl];
            const int ib = srcs[base + 8 + gl];
            union { uint4 u; _Float16 h[8]; } ca[8], cb[8];
#pragma unroll
            for (int j = 0; j < 8; ++j) {
                const int sa = __shfl(ia, grp * G + j);
                ca[j].u = *(const uint4*)(XW + (size_t)sa * LD + gl * 8);
            }
#pragma unroll
            for (int j = 0; j < 8; ++j) {
                const int sb = __shfl(ib, grp * G + j);
                cb[j].u = *(const uint4*)(XW + (size_t)sb * LD + gl * 8);
            }
#pragma unroll
            for (int j = 0; j < 8; ++j)
#pragma unroll
                for (int k = 0; k < 8; ++k) acc[k] += (float)ca[j].h[k];
#pragma unroll
            for (int j = 0; j < 8; ++j)
#pragma unroll
                for (int k = 0; k < 8; ++k) acc[k] += (float)cb[j].h[k];
            base += 16;
        }
        while (base + G <= s1) {               // 8-batch (at most one after 16-loop)
            const int myidx = srcs[base + gl];
            union { uint4 u; _Float16 h[8]; } cv[8];
#pragma unroll
            for (int j = 0; j < 8; ++j) {
                const int src = __shfl(myidx, grp * G + j);
                cv[j].u = *(const uint4*)(XW + (size_t)src * LD + gl * 8);
            }
#pragma unroll
            for (int j = 0; j < 8; ++j)
#pragma unroll
                for (int k = 0; k < 8; ++k) acc[k] += (float)cv[j].h[k];
            base += G;
        }
        if (base < s1) {                       // tail (1..7 edges)
            const int myidx = srcs[min(base + gl, s1 - 1)];
            const int rem = s1 - base;
            for (int j = 0; j < rem; ++j) {
                const int src = __shfl(myidx, grp * G + j);
                union { uint4 u; _Float16 h[8]; } cv;
                cv.u = *(const uint4*)(XW + (size_t)src * LD + gl * 8);
#pragma unroll
                for (int k = 0; k < 8; ++k) acc[k] += (float)cv.h[k];
            }
        }

        if (act) {
            const float dv = dinv[v];
            const float4 b0 = ((const float4*)bias)[gl * 2];
            const float4 b1 = ((const float4*)bias)[gl * 2 + 1];
            float o[8];
            o[0] = fmaxf(dv * acc[0] + b0.x, 0.f);
            o[1] = fmaxf(dv * acc[1] + b0.y, 0.f);
            o[2] = fmaxf(dv * acc[2] + b0.z, 0.f);
            o[3] = fmaxf(dv * acc[3] + b0.w, 0.f);
            o[4] = fmaxf(dv * acc[4] + b1.x, 0.f);
            o[5] = fmaxf(dv * acc[5] + b1.y, 0.f);
            o[6] = fmaxf(dv * acc[6] + b1.z, 0.f);
            o[7] = fmaxf(dv * acc[7] + b1.w, 0.f);
            if constexpr (sizeof(OT) == 2) {
                union { uint4 u; _Float16 h[8]; } ov;
#pragma unroll
                for (int k = 0; k < 8; ++k) ov.h[k] = (_Float16)o[k];
                *(uint4*)((_Float16*)out + (size_t)v * LD + gl * 8) = ov.u;
            } else {
                float* op = (float*)out + (size_t)v * LD + gl * 8;
                *(float4*)op       = make_float4(o[0], o[1], o[2], o[3]);
                *(float4*)(op + 4) = make_float4(o[4], o[5], o[6], o[7]);
            }
        }
    }
}

extern "C" void kernel_launch(void* const* d_in, const int* in_sizes, int n_in,
                              void* d_out, int out_size, void* d_ws, size_t ws_size,
                              hipStream_t stream) {
    const float* feats = (const float*)d_in[0];
    const int*   ei    = (const int*)d_in[1];
    const float* W1    = (const float*)d_in[2];
    const float* b1    = (const float*)d_in[3];
    const float* W2    = (const float*)d_in[4];
    const float* b2    = (const float*)d_in[5];
    const float* W3    = (const float*)d_in[6];
    const float* b3    = (const float*)d_in[7];

    const int N = in_sizes[0] / 128;
    const int E = in_sizes[1] / 2;
    const int* row = ei;       // source
    const int* col = ei + E;   // destination

    // workspace layout
    char* p = (char*)d_ws;
    unsigned* gHist = (unsigned*)p; p += ALIGNUP((size_t)256 * ABLK * 4);
    float*     dinv = (float*)p;    p += ALIGNUP((size_t)N * 4);
    int*       off  = (int*)p;      p += ALIGNUP((size_t)(N + 1) * 4);
    int*       srcs = (int*)p;      p += ALIGNUP((size_t)E * 4);
    f16x8*     wf1  = (f16x8*)p;    p += ALIGNUP((size_t)128 * 16 * 16);
    f16x8*     wf2  = (f16x8*)p;    p += ALIGNUP((size_t)128 * 16 * 16);
    f16x8*     wf3  = (f16x8*)p;    p += ALIGNUP((size_t)64 * 16 * 16);
    _Float16*  bufW = (_Float16*)p; p += ALIGNUP((size_t)N * 128 * 2);   // XW (gemm out)
    _Float16*  bufX = (_Float16*)p;                                       // h (gather out)
    unsigned* pairs = (unsigned*)bufX;  // alias: pairs consumed before gather1 writes bufX

    // ---- W fragment prep (one launch, all layers) ----
    wf_prep_all<<<20, 256, 0, stream>>>(W1, W2, W3, wf1, wf2, wf3);

    // ---- CSR build (no global atomics) ----
    const int chunk = (E + ABLK - 1) / ABLK;
    const int NB    = (N + 511) >> BSHIFT;
    bucket_hist_kernel<<<ABLK, 256, 0, stream>>>(col, gHist, E, chunk);
    bucket_scan_kernel<<<1, 1024, 0, stream>>>(gHist);
    bucket_scatter_kernel<<<ABLK, 256, 0, stream>>>(row, col, gHist, pairs, E, chunk);
    bucket_sort_kernel<<<NB, 512, 0, stream>>>(pairs, gHist, srcs, off, dinv, N, E);

    const int NCH = (N + 63) / 64;        // 64-row gemm chunks (one block each)
    const int GBg = (N + 31) / 32;        // gather: 4 waves x 8 groups = 32 nodes/block

    // ---- layer 1: feats(f32) @ W1 -> bufW (f16); agg (two 64-wide halves) -> bufX ----
    gemm_mfma<128, true><<<NCH, 256, 0, stream>>>(feats, wf1, dinv, bufW, N);
    gather_grp<128, _Float16><<<dim3(GBg, 2), 256, 0, stream>>>(bufW, off, srcs, dinv,
                                                                b1, bufX, N);
    // ---- layer 2 ----
    gemm_mfma<128, false><<<NCH, 256, 0, stream>>>(bufX, wf2, dinv, bufW, N);
    gather_grp<128, _Float16><<<dim3(GBg, 2), 256, 0, stream>>>(bufW, off, srcs, dinv,
                                                                b2, bufX, N);
    // ---- layer 3: DOUT=64; agg -> d_out (f32) ----
    gemm_mfma<64, false><<<NCH, 256, 0, stream>>>(bufX, wf3, dinv, bufW, N);
    gather_grp<64, float><<<dim3(GBg, 1), 256, 0, stream>>>(bufW, off, srcs, dinv, b3,
                                                            (float*)d_out, N);
}

// Round 12
// 279.456 us; speedup vs baseline: 1.4473x; 1.0482x over previous
//
#include <hip/hip_runtime.h>

#define ALIGNUP(x) (((x) + 255) & ~(size_t)255)
#define ABLK 256          // blocks for hist/scatter passes
#define BSHIFT 9          // 512 dst nodes per bucket; requires N <= 131072

typedef _Float16 f16x8 __attribute__((ext_vector_type(8)));
typedef float f32x4 __attribute__((ext_vector_type(4)));

// ---------------- CSR build: two-level counting sort, LDS atomics only ----------------

__global__ void bucket_hist_kernel(const int* __restrict__ col, unsigned* __restrict__ gHist,
                                   int nE, int chunk) {
    __shared__ unsigned hist[256];
    const int tid = threadIdx.x, blk = blockIdx.x;
    hist[tid] = 0;
    __syncthreads();
    const int e0 = blk * chunk, e1 = min(nE, e0 + chunk);
    for (int e = e0 + tid; e < e1; e += 256)
        atomicAdd(&hist[((unsigned)col[e]) >> BSHIFT], 1u);
    __syncthreads();
    gHist[tid * ABLK + blk] = hist[tid];   // bucket-major
}

__global__ void bucket_scan_kernel(unsigned* __restrict__ g) {
    __shared__ unsigned ps[1024];
    const int tid = threadIdx.x;
    const int base = tid * 64;
    unsigned sum = 0;
    for (int k = 0; k < 64; ++k) sum += g[base + k];
    ps[tid] = sum;
    __syncthreads();
    for (int o = 1; o < 1024; o <<= 1) {
        unsigned t = tid >= o ? ps[tid - o] : 0u;
        __syncthreads();
        ps[tid] += t;
        __syncthreads();
    }
    unsigned run = ps[tid] - sum;
    for (int k = 0; k < 64; ++k) {
        unsigned v = g[base + k];
        g[base + k] = run;
        run += v;
    }
}

__global__ void bucket_scatter_kernel(const int* __restrict__ row, const int* __restrict__ col,
                                      const unsigned* __restrict__ gScan,
                                      unsigned* __restrict__ pairs, int nE, int chunk) {
    __shared__ unsigned basec[256];
    const int tid = threadIdx.x, blk = blockIdx.x;
    basec[tid] = gScan[tid * ABLK + blk];
    __syncthreads();
    const int e0 = blk * chunk, e1 = min(nE, e0 + chunk);
    for (int e = e0 + tid; e < e1; e += 256) {
        unsigned d = (unsigned)col[e];
        unsigned pos = atomicAdd(&basec[d >> BSHIFT], 1u);
        pairs[pos] = (((unsigned)row[e]) << BSHIFT) | (d & 511u);  // src(17b) | dstLow(9b)
    }
}

__global__ void bucket_sort_kernel(const unsigned* __restrict__ pairs,
                                   const unsigned* __restrict__ gScan,
                                   int* __restrict__ srcs, int* __restrict__ off,
                                   float* __restrict__ dinv, int nN, int nE) {
    __shared__ unsigned cnt[512], sc[512];
    const int tid = threadIdx.x, b = blockIdx.x;
    const unsigned s = gScan[b * ABLK];
    const unsigned t = (b + 1 < 256) ? gScan[(b + 1) * ABLK] : (unsigned)nE;
    cnt[tid] = 0;
    __syncthreads();
    for (unsigned i = s + tid; i < t; i += 512)
        atomicAdd(&cnt[pairs[i] & 511u], 1u);
    __syncthreads();
    const unsigned v = cnt[tid];
    sc[tid] = v;
    __syncthreads();
    for (int o = 1; o < 512; o <<= 1) {
        unsigned q = tid >= o ? sc[tid - o] : 0u;
        __syncthreads();
        sc[tid] += q;
        __syncthreads();
    }
    const unsigned excl = sc[tid] - v;
    const int node = b * 512 + tid;
    if (node < nN) {
        dinv[node] = v > 0 ? rsqrtf((float)v) : 0.f;
        off[node] = (int)(s + excl);
    }
    if (b == 0 && tid == 0) off[nN] = nE;
    sc[tid] = excl;          // reuse as cursor
    __syncthreads();
    for (unsigned i = s + tid; i < t; i += 512) {
        unsigned p = pairs[i];
        unsigned pos = s + atomicAdd(&sc[p & 511u], 1u);
        srcs[pos] = (int)(p >> BSHIFT);
    }
}

// -------- W -> fragment-order f16 in GLOBAL memory (all 3 layers, one launch) --------

__global__ void wf_prep_all(const float* __restrict__ W1, const float* __restrict__ W2,
                            const float* __restrict__ W3, f16x8* __restrict__ wf1,
                            f16x8* __restrict__ wf2, f16x8* __restrict__ wf3) {
    const int c = blockIdx.x * blockDim.x + threadIdx.x;
    const float* W; f16x8* Wf; int DOUT, cc;
    if (c < 2048)      { W = W1; Wf = wf1; DOUT = 128; cc = c; }
    else if (c < 4096) { W = W2; Wf = wf2; DOUT = 128; cc = c - 2048; }
    else if (c < 5120) { W = W3; Wf = wf3; DOUT = 64;  cc = c - 4096; }
    else return;
    const int l = cc & 63;
    const int fk = (cc >> 6) & 3;
    const int j = cc >> 8;
    const int n = j * 16 + (l & 15);
    const int kbase = fk * 32 + ((l >> 4) * 8);
    f16x8 v;
#pragma unroll
    for (int e = 0; e < 8; ++e)
        v[e] = (_Float16)W[(size_t)(kbase + e) * DOUT + n];
    Wf[cc] = v;
}

// -------- MFMA GEMM, LDS-free: Yh[r] = f16(dinv[r] * (X[r,128] @ W[128,DOUT])) --------
// b-fragments read directly from global Wf: lane-consecutive 16B = coalesced 1KB reads,
// L2-resident (32KB total). No staging, no barriers, one 64-row chunk per block.

template <int DOUT, bool AF32>
__launch_bounds__(256)
__global__ void gemm_mfma(const void* __restrict__ Xv, const f16x8* __restrict__ Wf,
                          const float* __restrict__ dinv, _Float16* __restrict__ Y, int nrows) {
    constexpr int NTILE = DOUT / 16;
    const int lane = threadIdx.x & 63;
    const int wvid = threadIdx.x >> 6;
    const int m = lane & 15;
    const int kb = lane >> 4;
    const int r0 = blockIdx.x * 64 + wvid * 16;
    if (r0 >= nrows) return;
    const int arow = min(r0 + m, nrows - 1);

    f16x8 a[4];
    if constexpr (AF32) {
        const float* Xp = (const float*)Xv + (size_t)arow * 128 + kb * 8;
#pragma unroll
        for (int k = 0; k < 4; ++k) {
            const float4 x0 = *(const float4*)(Xp + k * 32);
            const float4 x1 = *(const float4*)(Xp + k * 32 + 4);
            f16x8 t;
            t[0] = (_Float16)x0.x; t[1] = (_Float16)x0.y;
            t[2] = (_Float16)x0.z; t[3] = (_Float16)x0.w;
            t[4] = (_Float16)x1.x; t[5] = (_Float16)x1.y;
            t[6] = (_Float16)x1.z; t[7] = (_Float16)x1.w;
            a[k] = t;
        }
    } else {
        const _Float16* Xp = (const _Float16*)Xv + (size_t)arow * 128 + kb * 8;
#pragma unroll
        for (int k = 0; k < 4; ++k) a[k] = *(const f16x8*)(Xp + k * 32);
    }

    f32x4 acc[NTILE];
#pragma unroll
    for (int j = 0; j < NTILE; ++j) acc[j] = (f32x4){0.f, 0.f, 0.f, 0.f};
#pragma unroll
    for (int k = 0; k < 4; ++k)
#pragma unroll
        for (int j = 0; j < NTILE; ++j)
            acc[j] = __builtin_amdgcn_mfma_f32_16x16x32_f16(
                         a[k], Wf[(j * 4 + k) * 64 + lane], acc[j], 0, 0, 0);

#pragma unroll
    for (int i = 0; i < 4; ++i) {
        const int r = r0 + kb * 4 + i;
        if (r < nrows) {
            const float dv = dinv[r];
#pragma unroll
            for (int j = 0; j < NTILE; ++j)
                Y[(size_t)r * DOUT + j * 16 + m] = (_Float16)(acc[j][i] * dv);
        }
    }
}

// -------- grouped CSR gather (r9 configuration — measured optimum) --------
// 64-wide slice per pass; blockIdx.y selects the feature half. 8 lanes own one dst node;
// src indices shfl-broadcast; 8 independent row loads per refill; no cross-lane reduce;
// fully-coalesced epilogue writes.

template <int LD, typename OT>
__launch_bounds__(256)
__global__ void gather_grp(const _Float16* __restrict__ XW, const int* __restrict__ off,
                           const int* __restrict__ srcs, const float* __restrict__ dinv,
                           const float* __restrict__ bias, OT* __restrict__ out, int nN) {
    constexpr int G = 8, GPW = 8;
    const int half = blockIdx.y;
    XW   += half * 64;
    bias += half * 64;
    out  += half * 64;
    const int lane = threadIdx.x & 63;
    const int gl   = lane % G;     // 16B chunk within the 64-wide slice
    const int grp  = lane / G;
    const int wid  = (blockIdx.x * blockDim.x + threadIdx.x) >> 6;
    const int nw   = (gridDim.x * blockDim.x) >> 6;

    for (int v0 = wid * GPW; v0 < nN; v0 += nw * GPW) {
        const int v   = v0 + grp;
        const bool act = v < nN;
        const int s0 = act ? off[v] : 0;
        const int s1 = act ? off[v + 1] : 0;
        float acc[8];
#pragma unroll
        for (int k = 0; k < 8; ++k) acc[k] = 0.f;

        int base = s0;
        while (base + G <= s1) {               // group-uniform condition
            const int myidx = srcs[base + gl];
#pragma unroll
            for (int j = 0; j < G; ++j) {
                const int src = __shfl(myidx, grp * G + j);
                union { uint4 u; _Float16 h[8]; } cv;
                cv.u = *(const uint4*)(XW + (size_t)src * LD + gl * 8);
#pragma unroll
                for (int k = 0; k < 8; ++k) acc[k] += (float)cv.h[k];
            }
            base += G;
        }
        if (base < s1) {                       // tail (group-uniform trip count)
            const int myidx = srcs[min(base + gl, s1 - 1)];
            const int rem = s1 - base;
            for (int j = 0; j < rem; ++j) {
                const int src = __shfl(myidx, grp * G + j);
                union { uint4 u; _Float16 h[8]; } cv;
                cv.u = *(const uint4*)(XW + (size_t)src * LD + gl * 8);
#pragma unroll
                for (int k = 0; k < 8; ++k) acc[k] += (float)cv.h[k];
            }
        }

        if (act) {
            const float dv = dinv[v];
            const float4 b0 = ((const float4*)bias)[gl * 2];
            const float4 b1 = ((const float4*)bias)[gl * 2 + 1];
            float o[8];
            o[0] = fmaxf(dv * acc[0] + b0.x, 0.f);
            o[1] = fmaxf(dv * acc[1] + b0.y, 0.f);
            o[2] = fmaxf(dv * acc[2] + b0.z, 0.f);
            o[3] = fmaxf(dv * acc[3] + b0.w, 0.f);
            o[4] = fmaxf(dv * acc[4] + b1.x, 0.f);
            o[5] = fmaxf(dv * acc[5] + b1.y, 0.f);
            o[6] = fmaxf(dv * acc[6] + b1.z, 0.f);
            o[7] = fmaxf(dv * acc[7] + b1.w, 0.f);
            if constexpr (sizeof(OT) == 2) {
                union { uint4 u; _Float16 h[8]; } ov;
#pragma unroll
                for (int k = 0; k < 8; ++k) ov.h[k] = (_Float16)o[k];
                *(uint4*)((_Float16*)out + (size_t)v * LD + gl * 8) = ov.u;
            } else {
                float* op = (float*)out + (size_t)v * LD + gl * 8;
                *(float4*)op       = make_float4(o[0], o[1], o[2], o[3]);
                *(float4*)(op + 4) = make_float4(o[4], o[5], o[6], o[7]);
            }
        }
    }
}

extern "C" void kernel_launch(void* const* d_in, const int* in_sizes, int n_in,
                              void* d_out, int out_size, void* d_ws, size_t ws_size,
                              hipStream_t stream) {
    const float* feats = (const float*)d_in[0];
    const int*   ei    = (const int*)d_in[1];
    const float* W1    = (const float*)d_in[2];
    const float* b1    = (const float*)d_in[3];
    const float* W2    = (const float*)d_in[4];
    const float* b2    = (const float*)d_in[5];
    const float* W3    = (const float*)d_in[6];
    const float* b3    = (const float*)d_in[7];

    const int N = in_sizes[0] / 128;
    const int E = in_sizes[1] / 2;
    const int* row = ei;       // source
    const int* col = ei + E;   // destination

    // workspace layout
    char* p = (char*)d_ws;
    unsigned* gHist = (unsigned*)p; p += ALIGNUP((size_t)256 * ABLK * 4);
    float*     dinv = (float*)p;    p += ALIGNUP((size_t)N * 4);
    int*       off  = (int*)p;      p += ALIGNUP((size_t)(N + 1) * 4);
    int*       srcs = (int*)p;      p += ALIGNUP((size_t)E * 4);
    f16x8*     wf1  = (f16x8*)p;    p += ALIGNUP((size_t)128 * 16 * 16);
    f16x8*     wf2  = (f16x8*)p;    p += ALIGNUP((size_t)128 * 16 * 16);
    f16x8*     wf3  = (f16x8*)p;    p += ALIGNUP((size_t)64 * 16 * 16);
    _Float16*  bufW = (_Float16*)p; p += ALIGNUP((size_t)N * 128 * 2);   // XW (gemm out)
    _Float16*  bufX = (_Float16*)p;                                       // h (gather out)
    unsigned* pairs = (unsigned*)bufX;  // alias: pairs consumed before gather1 writes bufX

    // ---- W fragment prep (one launch, all layers) ----
    wf_prep_all<<<20, 256, 0, stream>>>(W1, W2, W3, wf1, wf2, wf3);

    // ---- CSR build (no global atomics) ----
    const int chunk = (E + ABLK - 1) / ABLK;
    const int NB    = (N + 511) >> BSHIFT;
    bucket_hist_kernel<<<ABLK, 256, 0, stream>>>(col, gHist, E, chunk);
    bucket_scan_kernel<<<1, 1024, 0, stream>>>(gHist);
    bucket_scatter_kernel<<<ABLK, 256, 0, stream>>>(row, col, gHist, pairs, E, chunk);
    bucket_sort_kernel<<<NB, 512, 0, stream>>>(pairs, gHist, srcs, off, dinv, N, E);

    const int NCH = (N + 63) / 64;        // 64-row gemm chunks (one block each)
    const int GBg = (N + 31) / 32;        // gather: 4 waves x 8 groups = 32 nodes/block

    // ---- layer 1: feats(f32) @ W1 -> bufW (f16); agg (two 64-wide halves) -> bufX ----
    gemm_mfma<128, true><<<NCH, 256, 0, stream>>>(feats, wf1, dinv, bufW, N);
    gather_grp<128, _Float16><<<dim3(GBg, 2), 256, 0, stream>>>(bufW, off, srcs, dinv,
                                                                b1, bufX, N);
    // ---- layer 2 ----
    gemm_mfma<128, false><<<NCH, 256, 0, stream>>>(bufX, wf2, dinv, bufW, N);
    gather_grp<128, _Float16><<<dim3(GBg, 2), 256, 0, stream>>>(bufW, off, srcs, dinv,
                                                                b2, bufX, N);
    // ---- layer 3: DOUT=64; agg -> d_out (f32) ----
    gemm_mfma<64, false><<<NCH, 256, 0, stream>>>(bufX, wf3, dinv, bufW, N);
    gather_grp<64, float><<<dim3(GBg, 1), 256, 0, stream>>>(bufW, off, srcs, dinv, b3,
                                                            (float*)d_out, N);
}